// Round 11
// baseline (873.922 us; speedup 1.0000x reference)
//
#include <hip/hip_runtime.h>

typedef __attribute__((ext_vector_type(8))) short bf16x8;
typedef __attribute__((ext_vector_type(4))) float f32x4;

#define DEVI static __device__ __forceinline__

DEVI float bf2f(unsigned int u) { unsigned int v = u << 16; float f; __builtin_memcpy(&f, &v, 4); return f; }
DEVI unsigned short f2bf(float f) { unsigned int v; __builtin_memcpy(&v, &f, 4); v += 0x7fffu + ((v >> 16) & 1u); return (unsigned short)(v >> 16); }
DEVI unsigned int pk2(float a, float b) { return (unsigned)f2bf(a) | ((unsigned)f2bf(b) << 16); }

#define NTOK 785
#define CH 768
#define NH 12
#define MROWS 12560   // 16*785
#define LEFT 549

DEVI void loadrow(const float* p, uint4& u0, uint4& u1) {
  float4 f0 = *(const float4*)p;
  float4 f1 = *(const float4*)(p + 4);
  float4 f2 = *(const float4*)(p + 8);
  float4 f3 = *(const float4*)(p + 12);
  u0 = (uint4){pk2(f0.x, f0.y), pk2(f0.z, f0.w), pk2(f1.x, f1.y), pk2(f1.z, f1.w)};
  u1 = (uint4){pk2(f2.x, f2.y), pk2(f2.z, f2.w), pk2(f3.x, f3.y), pk2(f3.z, f3.w)};
}
DEVI void loadrow(const unsigned short* p, uint4& u0, uint4& u1) {
  u0 = *(const uint4*)p;
  u1 = *(const uint4*)(p + 8);
}

// ---------------- GEMM: C[m,n] = sum_k A[m,k] * W[n,k] (+bias), 128x128 tile ----------------
template<int MODE, typename TA, typename TW, typename TO>
__global__ __launch_bounds__(256) void gemm128(
    const TA* __restrict__ A,
    const TW* __restrict__ W,
    const float* __restrict__ bias,
    TO* __restrict__ o0,
    unsigned short* __restrict__ o1,
    unsigned short* __restrict__ o2)
{
  __shared__ __align__(16) short As[128 * 40];
  __shared__ __align__(16) short Bs[128 * 40];
  const int tid = threadIdx.x;
  const int wave = tid >> 6, lane = tid & 63, l15 = lane & 15, quad = lane >> 4;
  const int m0 = blockIdx.x * 128, n0 = blockIdx.y * 128;
  const int mw = (wave >> 1) * 64, nw = (wave & 1) * 64;
  f32x4 acc[4][4];
  #pragma unroll
  for (int i = 0; i < 4; ++i)
    #pragma unroll
    for (int j = 0; j < 4; ++j) acc[i][j] = (f32x4){0.f, 0.f, 0.f, 0.f};

  const int sr = tid >> 1, sk = (tid & 1) * 16;
  int arow = m0 + sr; if (arow > MROWS - 1) arow = MROWS - 1;
  const TA* Ap = A + arow * CH + sk;
  const TW* Bp = W + (n0 + sr) * CH + sk;
  short* aw = As + sr * 40 + sk;
  short* bw = Bs + sr * 40 + sk;

  uint4 a0, a1, b0, b1;
  loadrow(Ap, a0, a1);
  loadrow(Bp, b0, b1);

  for (int kt = 0; kt < 24; ++kt) {
    __syncthreads();
    *(uint4*)(aw) = a0; *(uint4*)(aw + 8) = a1;
    *(uint4*)(bw) = b0; *(uint4*)(bw + 8) = b1;
    __syncthreads();
    if (kt < 23) {
      loadrow(Ap + (kt + 1) * 32, a0, a1);
      loadrow(Bp + (kt + 1) * 32, b0, b1);
    }
    bf16x8 af[4], bfr[4];
    #pragma unroll
    for (int i = 0; i < 4; ++i)
      af[i] = *(const bf16x8*)(As + (mw + i * 16 + l15) * 40 + quad * 8);
    #pragma unroll
    for (int j = 0; j < 4; ++j)
      bfr[j] = *(const bf16x8*)(Bs + (nw + j * 16 + l15) * 40 + quad * 8);
    #pragma unroll
    for (int i = 0; i < 4; ++i)
      #pragma unroll
      for (int j = 0; j < 4; ++j)
        acc[i][j] = __builtin_amdgcn_mfma_f32_16x16x32_bf16(af[i], bfr[j], acc[i][j], 0, 0, 0);
  }

  #pragma unroll
  for (int i = 0; i < 4; ++i) {
    const int mbase = m0 + mw + i * 16 + quad * 4;
    #pragma unroll
    for (int j = 0; j < 4; ++j) {
      const int nbase = n0 + nw + j * 16;
      if (MODE == 0) {
        const int t = (nbase >= 1536) ? 2 : ((nbase >= 768) ? 1 : 0);
        const int rem = nbase - t * 768;
        const int h = rem >> 6;
        const int hd = (rem & 63) + l15;
        unsigned short* dst = (t == 0) ? (unsigned short*)o0 : ((t == 1) ? o1 : o2);
        #pragma unroll
        for (int r = 0; r < 4; ++r) {
          const int mm = mbase + r;
          if (mm < MROWS) {
            const int b = mm / NTOK, nn = mm - b * NTOK;
            dst[((b * NH + h) * NTOK + nn) * 64 + hd] = f2bf(acc[i][j][r]);
          }
        }
      } else {
        const int n = nbase + l15;
        const float bv = bias[n];
        #pragma unroll
        for (int r = 0; r < 4; ++r) {
          const int mm = mbase + r;
          if (mm < MROWS) ((float*)o0)[mm * CH + n] = acc[i][j][r] + bv;
        }
      }
    }
  }
}

// ---------------- Flash attention ----------------
__global__ __launch_bounds__(256) void flash(
    const unsigned short* __restrict__ qW,
    const unsigned short* __restrict__ kW,
    const unsigned short* __restrict__ vW,
    unsigned short* __restrict__ ao)
{
  __shared__ __align__(16) short Ks[32 * 72];
  __shared__ __align__(16) short Vts[64 * 40];
  __shared__ __align__(16) short Ps[4][16 * 40];
  const int tid = threadIdx.x;
  const int wave = tid >> 6, lane = tid & 63, l15 = lane & 15, quad = lane >> 4;
  const int qt = blockIdx.x, bh = blockIdx.y;
  const int qbase = qt * 64 + wave * 16;
  int qrow = qbase + l15; if (qrow > NTOK - 1) qrow = NTOK - 1;
  const unsigned short* qp = qW + (bh * NTOK + qrow) * 64;
  bf16x8 aq[2];
  aq[0] = *(const bf16x8*)(qp + quad * 8);
  aq[1] = *(const bf16x8*)(qp + 32 + quad * 8);

  f32x4 o[4];
  float mi[4], li[4];
  #pragma unroll
  for (int r = 0; r < 4; ++r) { mi[r] = -1e30f; li[r] = 0.f; }
  #pragma unroll
  for (int d = 0; d < 4; ++d) o[d] = (f32x4){0.f, 0.f, 0.f, 0.f};

  const int skey = tid >> 3, sd = (tid & 7) * 8;

  for (int kt = 0; kt < 25; ++kt) {
    const int key = kt * 32 + skey;
    const int krow = key > NTOK - 1 ? NTOK - 1 : key;
    __syncthreads();
    *(uint4*)(Ks + skey * 72 + sd) = *(const uint4*)(kW + (bh * NTOK + krow) * 64 + sd);
    uint4 vv = *(const uint4*)(vW + (bh * NTOK + krow) * 64 + sd);
    unsigned short ve[8] = {
      (unsigned short)(vv.x & 0xffff), (unsigned short)(vv.x >> 16),
      (unsigned short)(vv.y & 0xffff), (unsigned short)(vv.y >> 16),
      (unsigned short)(vv.z & 0xffff), (unsigned short)(vv.z >> 16),
      (unsigned short)(vv.w & 0xffff), (unsigned short)(vv.w >> 16)};
    #pragma unroll
    for (int i = 0; i < 8; ++i) Vts[(sd + i) * 40 + skey] = (short)ve[i];
    __syncthreads();

    f32x4 s0 = (f32x4){0.f,0.f,0.f,0.f}, s1 = (f32x4){0.f,0.f,0.f,0.f};
    #pragma unroll
    for (int kk = 0; kk < 2; ++kk) {
      bf16x8 bk0 = *(const bf16x8*)(Ks + l15 * 72 + kk * 32 + quad * 8);
      bf16x8 bk1 = *(const bf16x8*)(Ks + (16 + l15) * 72 + kk * 32 + quad * 8);
      s0 = __builtin_amdgcn_mfma_f32_16x16x32_bf16(aq[kk], bk0, s0, 0, 0, 0);
      s1 = __builtin_amdgcn_mfma_f32_16x16x32_bf16(aq[kk], bk1, s1, 0, 0, 0);
    }
    const int key0 = kt * 32 + l15, key1 = kt * 32 + 16 + l15;
    short* pw = &Ps[wave][0];
    #pragma unroll
    for (int r = 0; r < 4; ++r) {
      float v0 = s0[r] * 0.125f; if (key0 > NTOK - 1) v0 = -1e30f;
      float v1 = s1[r] * 0.125f; if (key1 > NTOK - 1) v1 = -1e30f;
      float t = fmaxf(v0, v1);
      t = fmaxf(t, __shfl_xor(t, 1));
      t = fmaxf(t, __shfl_xor(t, 2));
      t = fmaxf(t, __shfl_xor(t, 4));
      t = fmaxf(t, __shfl_xor(t, 8));
      const float mn = fmaxf(mi[r], t);
      const float al = __expf(mi[r] - mn);
      const float p0 = __expf(v0 - mn);
      const float p1 = __expf(v1 - mn);
      float rs = p0 + p1;
      rs += __shfl_xor(rs, 1);
      rs += __shfl_xor(rs, 2);
      rs += __shfl_xor(rs, 4);
      rs += __shfl_xor(rs, 8);
      li[r] = li[r] * al + rs;
      mi[r] = mn;
      o[0][r] *= al; o[1][r] *= al; o[2][r] *= al; o[3][r] *= al;
      pw[(quad * 4 + r) * 40 + l15] = (short)f2bf(p0);
      pw[(quad * 4 + r) * 40 + 16 + l15] = (short)f2bf(p1);
    }
    bf16x8 ap = *(const bf16x8*)(pw + l15 * 40 + quad * 8);
    #pragma unroll
    for (int dg = 0; dg < 4; ++dg) {
      bf16x8 bv = *(const bf16x8*)(Vts + (dg * 16 + l15) * 40 + quad * 8);
      o[dg] = __builtin_amdgcn_mfma_f32_16x16x32_bf16(ap, bv, o[dg], 0, 0, 0);
    }
  }

  const int b = bh / NH, h = bh - b * NH;
  #pragma unroll
  for (int r = 0; r < 4; ++r) {
    const int q = qbase + quad * 4 + r;
    if (q < NTOK) {
      const float inv = 1.f / li[r];
      #pragma unroll
      for (int dg = 0; dg < 4; ++dg)
        ao[(b * NTOK + q) * CH + h * 64 + dg * 16 + l15] = f2bf(o[dg][r] * inv);
    }
  }
}

// ================= BLAS-faithful f32 cls chain + numpy-SIMD exp =================

__global__ __launch_bounds__(64) void q0_kernel(
    const float* __restrict__ x, const float* __restrict__ Wqkv, float* __restrict__ q0f)
{
  const int bh = blockIdx.x;
  const int b = bh / NH, h = bh - b * NH;
  const int d = threadIdx.x;
  const float* xr = x + (b * NTOK) * CH;
  const float* wr = Wqkv + (h * 64 + d) * CH;
  float p0 = 0.f, p1 = 0.f;
  for (int c = 0; c < 384; ++c) p0 = __fmaf_rn(xr[c], wr[c], p0);
  for (int c = 384; c < CH; ++c) p1 = __fmaf_rn(xr[c], wr[c], p1);
  q0f[bh * 64 + d] = __fadd_rn(p0, p1);
}

// kf[(bh*785+j)*64+d]: two KC=384 phases, each sequential-k FMA; combine with one add.
__global__ __launch_bounds__(256) void kf_gemm(
    const float* __restrict__ x, const float* __restrict__ Wqkv, float* __restrict__ kf)
{
  __shared__ float Xs[64][33];
  __shared__ float Ws[64][33];
  const int bh = blockIdx.x;   // 0..191
  const int jt = blockIdx.y;   // 0..12
  const int b = bh / NH, h = bh - b * NH;
  const int tid = threadIdx.x;
  const int td = tid & 15, tj = tid >> 4;
  float accA[4][4];
  float out0[4][4];
  #pragma unroll
  for (int jj = 0; jj < 4; ++jj)
    #pragma unroll
    for (int dd = 0; dd < 4; ++dd) accA[jj][dd] = 0.f;

  for (int phase = 0; phase < 2; ++phase) {
    const int kbase = phase * 384;
    for (int kc = 0; kc < 384; kc += 32) {
      __syncthreads();
      #pragma unroll
      for (int pass = 0; pass < 2; ++pass) {
        const int row = (tid >> 3) + pass * 32;
        const int col = (tid & 7) * 4;
        int j = jt * 64 + row; if (j > NTOK - 1) j = NTOK - 1;
        float4 xv = *(const float4*)(x + (b * NTOK + j) * CH + kbase + kc + col);
        Xs[row][col] = xv.x; Xs[row][col + 1] = xv.y; Xs[row][col + 2] = xv.z; Xs[row][col + 3] = xv.w;
        float4 wv = *(const float4*)(Wqkv + (CH + h * 64 + row) * CH + kbase + kc + col);
        Ws[row][col] = wv.x; Ws[row][col + 1] = wv.y; Ws[row][col + 2] = wv.z; Ws[row][col + 3] = wv.w;
      }
      __syncthreads();
      #pragma unroll 8
      for (int kk = 0; kk < 32; ++kk) {
        float av[4], bv[4];
        #pragma unroll
        for (int jj = 0; jj < 4; ++jj) av[jj] = Xs[tj * 4 + jj][kk];
        #pragma unroll
        for (int dd = 0; dd < 4; ++dd) bv[dd] = Ws[td * 4 + dd][kk];
        #pragma unroll
        for (int jj = 0; jj < 4; ++jj)
          #pragma unroll
          for (int dd = 0; dd < 4; ++dd)
            accA[jj][dd] = __fmaf_rn(av[jj], bv[dd], accA[jj][dd]);
      }
    }
    if (phase == 0) {
      #pragma unroll
      for (int jj = 0; jj < 4; ++jj)
        #pragma unroll
        for (int dd = 0; dd < 4; ++dd) { out0[jj][dd] = accA[jj][dd]; accA[jj][dd] = 0.f; }
    }
  }
  #pragma unroll
  for (int jj = 0; jj < 4; ++jj) {
    const int j = jt * 64 + tj * 4 + jj;
    if (j <= NTOK - 1) {
      #pragma unroll
      for (int dd = 0; dd < 4; ++dd)
        kf[(bh * NTOK + j) * 64 + td * 4 + dd] = __fadd_rn(out0[jj][dd], accA[jj][dd]);
    }
  }
}

DEVI float np_block8(const float* a, int off, int n) {
  float r[8];
  #pragma unroll
  for (int i = 0; i < 8; ++i) r[i] = a[off + i];
  int i = 8;
  const int lim = n - (n & 7);
  for (; i < lim; i += 8) {
    #pragma unroll
    for (int j = 0; j < 8; ++j) r[j] = __fadd_rn(r[j], a[off + i + j]);
  }
  float res = __fadd_rn(__fadd_rn(__fadd_rn(r[0], r[1]), __fadd_rn(r[2], r[3])),
                        __fadd_rn(__fadd_rn(r[4], r[5]), __fadd_rn(r[6], r[7])));
  for (; i < n; ++i) res = __fadd_rn(res, a[off + i]);
  return res;
}
DEVI float np_sum785(const float* a) {
  float p392 = __fadd_rn(__fadd_rn(np_block8(a, 0, 96),   np_block8(a, 96, 96)),
                         __fadd_rn(np_block8(a, 192, 96), np_block8(a, 288, 104)));
  float p393 = __fadd_rn(__fadd_rn(np_block8(a, 392, 96), np_block8(a, 488, 96)),
                         __fadd_rn(np_block8(a, 584, 96), np_block8(a, 680, 105)));
  return __fadd_rn(p392, p393);
}

// numpy SIMD f32 exp (loops_exponent_log.dispatch.c.src): Cody-Waite + rational P(5)/Q(2),
// FMA Horner, exact power-of-2 scale. Bit-faithful for in-range inputs (no over/underflow).
DEVI float np_expf(float x) {
  const float q = rintf(__fmul_rn(x, 1.442695040888963407f));   // NPY_LOG2Ef, rint = nearest-even
  float r = __fmaf_rn(q, -0.693145751953125f, x);                // CODY_WAITE_LOGE_2_HIGHf (exact)
  r = __fmaf_rn(q, -1.428606765330187045e-06f, r);               // CODY_WAITE_LOGE_2_LOWf
  float num = __fmaf_rn(r, 5.082762527590693718096e-04f, 6.757896990527504603057e-03f); // P5,P4
  num = __fmaf_rn(num, r, 5.114512081637298353406e-02f);         // P3
  num = __fmaf_rn(num, r, 2.473615434895520810817e-01f);         // P2
  num = __fmaf_rn(num, r, 7.257664613233124478488e-01f);         // P1
  num = __fmaf_rn(num, r, 9.999999999980870924916e-01f);         // P0
  float den = __fmaf_rn(r, 2.159509375685829852307e-02f, -2.742335390411667452936e-01f); // Q2,Q1
  den = __fmaf_rn(den, r, 1.0f);                                 // Q0
  return ldexpf(__fdiv_rn(num, den), (int)q);
}

__global__ __launch_bounds__(256) void cls_logits32(
    const float* __restrict__ kf, const float* __restrict__ q0f, float* __restrict__ part)
{
  __shared__ float q0s[64];
  __shared__ float lg[NTOK];
  __shared__ float ev[NTOK];
  __shared__ float red[256];
  const int bh = blockIdx.x;
  const int tid = threadIdx.x;
  if (tid < 64) q0s[tid] = q0f[bh * 64 + tid];
  __syncthreads();

  for (int j = tid; j < NTOK; j += 256) {
    const float* kr = kf + (bh * NTOK + j) * 64;
    float acc = 0.f;
    #pragma unroll
    for (int d = 0; d < 64; ++d) acc = __fmaf_rn(q0s[d], kr[d], acc);
    lg[j] = __fmul_rn(acc, 0.125f);
  }
  __syncthreads();

  float lm = -1e30f;
  for (int j = tid; j < NTOK; j += 256) lm = fmaxf(lm, lg[j]);
  red[tid] = lm; __syncthreads();
  for (int s = 128; s > 0; s >>= 1) {
    if (tid < s) red[tid] = fmaxf(red[tid], red[tid + s]);
    __syncthreads();
  }
  const float m = red[0];
  __syncthreads();

  for (int j = tid; j < NTOK; j += 256)
    ev[j] = np_expf(__fsub_rn(lg[j], m));
  __syncthreads();
  if (tid == 0) red[0] = np_sum785(ev);
  __syncthreads();
  const float Z = red[0];
  for (int j = tid; j < NTOK; j += 256)
    if (j >= 1) part[bh * 784 + (j - 1)] = __fdiv_rn(ev[j], Z);
}

__global__ __launch_bounds__(256) void cls_reduce32(
    const float* __restrict__ part, float* __restrict__ cls, float* __restrict__ cls_out)
{
  const int i = blockIdx.x * 256 + threadIdx.x;
  if (i >= 16 * 784) return;
  const int b = i / 784, t = i - b * 784;
  float s = part[(b * NH) * 784 + t];
  #pragma unroll
  for (int h = 1; h < NH; ++h) s = __fadd_rn(s, part[(b * NH + h) * 784 + t]);
  const float c = __fdiv_rn(s, 12.0f);
  cls[i] = c;
  cls_out[i] = c;
}

// Stable descending top-k (smaller index first on ties).
__global__ __launch_bounds__(256) void topk32(
    const float* __restrict__ cls, float* __restrict__ idx_out)
{
  __shared__ float vals[784];
  const int b = blockIdx.x, tid = threadIdx.x;
  for (int i = tid; i < 784; i += 256) vals[i] = cls[b * 784 + i];
  __syncthreads();
  for (int i = tid; i < 784; i += 256) {
    const float vi = vals[i];
    int rank = 0;
    for (int j = 0; j < 784; ++j) {
      const float vj = vals[j];
      rank += ((vj > vi) || (vj == vi && j < i)) ? 1 : 0;
    }
    if (rank < LEFT) idx_out[b * LEFT + rank] = (float)i;
  }
}

__global__ __launch_bounds__(256) void bcast_index(
    const float* __restrict__ idx, float* __restrict__ index_out)
{
  const int e = blockIdx.x * 256 + threadIdx.x;
  const int base = e * 8;
  if (base + 8 > 6746112) return;
  const int row = base / CH;
  const float v = idx[row];
  float4 q = {v, v, v, v};
  *(float4*)(index_out + base) = q;
  *(float4*)(index_out + base + 4) = q;
}

extern "C" void kernel_launch(void* const* d_in, const int* in_sizes, int n_in,
                              void* d_out, int out_size, void* d_ws, size_t ws_size,
                              hipStream_t stream) {
  const float* x     = (const float*)d_in[0];
  const float* Wqkv  = (const float*)d_in[1];
  const float* Wproj = (const float*)d_in[2];
  const float* bproj = (const float*)d_in[3];
  float* out = (float*)d_out;

  // d_out element offsets (f32): out | idx | index | cls_attn
  float* out_idx   = out + 9646080;
  float* out_index = out + 9654864;
  float* out_cls   = out + 16400976;

  char* ws = (char*)d_ws;
  unsigned short* qW  = (unsigned short*)(ws);               // 19,292,160 B
  unsigned short* kW  = (unsigned short*)(ws + 19292160);    // 19,292,160 B
  unsigned short* vW  = (unsigned short*)(ws + 38584320);    // 19,292,160 B
  unsigned short* aoW = (unsigned short*)(ws + 57876480);    // 19,292,160 B
  float* kf   = (float*)(ws);                                // 38,584,320 B (overlaps qW+kW, used after flash)
  float* q0f  = (float*)(ws + 38584320);                     // 49,152 B
  float* part = (float*)(ws + 38633472);                     // 602,112 B
  float* cls  = (float*)(ws + 39235584);                     // 50,176 B

  // 1) qkv projection -> q,k,v [B,H,N,64] bf16
  gemm128<0, float, float, unsigned short><<<dim3(99, 18), 256, 0, stream>>>(x, Wqkv, nullptr, qW, kW, vW);
  // 2) flash attention -> [B,N,C] bf16
  flash<<<dim3(13, 192), 256, 0, stream>>>(qW, kW, vW, aoW);
  // 3) output projection + bias -> f32 d_out[0 : 9646080]
  gemm128<1, unsigned short, float, float><<<dim3(99, 6), 256, 0, stream>>>(aoW, Wproj, bproj, out, nullptr, nullptr);
  // 4) BLAS-faithful f32 cls chain with numpy-SIMD exp (q/k/v regions now dead)
  q0_kernel<<<192, 64, 0, stream>>>(x, Wqkv, q0f);
  kf_gemm<<<dim3(192, 13), 256, 0, stream>>>(x, Wqkv, kf);
  cls_logits32<<<192, 256, 0, stream>>>(kf, q0f, part);
  cls_reduce32<<<49, 256, 0, stream>>>(part, cls, out_cls);
  // 5) top-k + index broadcast
  topk32<<<16, 256, 0, stream>>>(cls, out_idx);
  bcast_index<<<3294, 256, 0, stream>>>(out_idx, out_index);
}

// Round 12
// 792.696 us; speedup vs baseline: 1.1025x; 1.1025x over previous
//
#include <hip/hip_runtime.h>

typedef __attribute__((ext_vector_type(8))) short bf16x8;
typedef __attribute__((ext_vector_type(4))) float f32x4;

#define DEVI static __device__ __forceinline__

DEVI float bf2f(unsigned int u) { unsigned int v = u << 16; float f; __builtin_memcpy(&f, &v, 4); return f; }
DEVI unsigned short f2bf(float f) { unsigned int v; __builtin_memcpy(&v, &f, 4); v += 0x7fffu + ((v >> 16) & 1u); return (unsigned short)(v >> 16); }
DEVI unsigned int pk2(float a, float b) { return (unsigned)f2bf(a) | ((unsigned)f2bf(b) << 16); }

#define NTOK 785
#define CH 768
#define NH 12
#define MROWS 12560   // 16*785
#define LEFT 549

DEVI void loadrow(const float* p, uint4& u0, uint4& u1) {
  float4 f0 = *(const float4*)p;
  float4 f1 = *(const float4*)(p + 4);
  float4 f2 = *(const float4*)(p + 8);
  float4 f3 = *(const float4*)(p + 12);
  u0 = (uint4){pk2(f0.x, f0.y), pk2(f0.z, f0.w), pk2(f1.x, f1.y), pk2(f1.z, f1.w)};
  u1 = (uint4){pk2(f2.x, f2.y), pk2(f2.z, f2.w), pk2(f3.x, f3.y), pk2(f3.z, f3.w)};
}
DEVI void loadrow(const unsigned short* p, uint4& u0, uint4& u1) {
  u0 = *(const uint4*)p;
  u1 = *(const uint4*)(p + 8);
}

// ---------------- GEMM: C[m,n] = sum_k A[m,k] * W[n,k] (+bias), 128x128 tile ----------------
template<int MODE, typename TA, typename TW, typename TO>
__global__ __launch_bounds__(256) void gemm128(
    const TA* __restrict__ A,
    const TW* __restrict__ W,
    const float* __restrict__ bias,
    TO* __restrict__ o0,
    unsigned short* __restrict__ o1,
    unsigned short* __restrict__ o2)
{
  __shared__ __align__(16) short As[128 * 40];
  __shared__ __align__(16) short Bs[128 * 40];
  const int tid = threadIdx.x;
  const int wave = tid >> 6, lane = tid & 63, l15 = lane & 15, quad = lane >> 4;
  const int m0 = blockIdx.x * 128, n0 = blockIdx.y * 128;
  const int mw = (wave >> 1) * 64, nw = (wave & 1) * 64;
  f32x4 acc[4][4];
  #pragma unroll
  for (int i = 0; i < 4; ++i)
    #pragma unroll
    for (int j = 0; j < 4; ++j) acc[i][j] = (f32x4){0.f, 0.f, 0.f, 0.f};

  const int sr = tid >> 1, sk = (tid & 1) * 16;
  int arow = m0 + sr; if (arow > MROWS - 1) arow = MROWS - 1;
  const TA* Ap = A + arow * CH + sk;
  const TW* Bp = W + (n0 + sr) * CH + sk;
  short* aw = As + sr * 40 + sk;
  short* bw = Bs + sr * 40 + sk;

  uint4 a0, a1, b0, b1;
  loadrow(Ap, a0, a1);
  loadrow(Bp, b0, b1);

  for (int kt = 0; kt < 24; ++kt) {
    __syncthreads();
    *(uint4*)(aw) = a0; *(uint4*)(aw + 8) = a1;
    *(uint4*)(bw) = b0; *(uint4*)(bw + 8) = b1;
    __syncthreads();
    if (kt < 23) {
      loadrow(Ap + (kt + 1) * 32, a0, a1);
      loadrow(Bp + (kt + 1) * 32, b0, b1);
    }
    bf16x8 af[4], bfr[4];
    #pragma unroll
    for (int i = 0; i < 4; ++i)
      af[i] = *(const bf16x8*)(As + (mw + i * 16 + l15) * 40 + quad * 8);
    #pragma unroll
    for (int j = 0; j < 4; ++j)
      bfr[j] = *(const bf16x8*)(Bs + (nw + j * 16 + l15) * 40 + quad * 8);
    #pragma unroll
    for (int i = 0; i < 4; ++i)
      #pragma unroll
      for (int j = 0; j < 4; ++j)
        acc[i][j] = __builtin_amdgcn_mfma_f32_16x16x32_bf16(af[i], bfr[j], acc[i][j], 0, 0, 0);
  }

  #pragma unroll
  for (int i = 0; i < 4; ++i) {
    const int mbase = m0 + mw + i * 16 + quad * 4;
    #pragma unroll
    for (int j = 0; j < 4; ++j) {
      const int nbase = n0 + nw + j * 16;
      if (MODE == 0) {
        const int t = (nbase >= 1536) ? 2 : ((nbase >= 768) ? 1 : 0);
        const int rem = nbase - t * 768;
        const int h = rem >> 6;
        const int hd = (rem & 63) + l15;
        unsigned short* dst = (t == 0) ? (unsigned short*)o0 : ((t == 1) ? o1 : o2);
        #pragma unroll
        for (int r = 0; r < 4; ++r) {
          const int mm = mbase + r;
          if (mm < MROWS) {
            const int b = mm / NTOK, nn = mm - b * NTOK;
            dst[((b * NH + h) * NTOK + nn) * 64 + hd] = f2bf(acc[i][j][r]);
          }
        }
      } else {
        const int n = nbase + l15;
        const float bv = bias[n];
        #pragma unroll
        for (int r = 0; r < 4; ++r) {
          const int mm = mbase + r;
          if (mm < MROWS) ((float*)o0)[mm * CH + n] = acc[i][j][r] + bv;
        }
      }
    }
  }
}

// ---------------- Flash attention ----------------
__global__ __launch_bounds__(256) void flash(
    const unsigned short* __restrict__ qW,
    const unsigned short* __restrict__ kW,
    const unsigned short* __restrict__ vW,
    unsigned short* __restrict__ ao)
{
  __shared__ __align__(16) short Ks[32 * 72];
  __shared__ __align__(16) short Vts[64 * 40];
  __shared__ __align__(16) short Ps[4][16 * 40];
  const int tid = threadIdx.x;
  const int wave = tid >> 6, lane = tid & 63, l15 = lane & 15, quad = lane >> 4;
  const int qt = blockIdx.x, bh = blockIdx.y;
  const int qbase = qt * 64 + wave * 16;
  int qrow = qbase + l15; if (qrow > NTOK - 1) qrow = NTOK - 1;
  const unsigned short* qp = qW + (bh * NTOK + qrow) * 64;
  bf16x8 aq[2];
  aq[0] = *(const bf16x8*)(qp + quad * 8);
  aq[1] = *(const bf16x8*)(qp + 32 + quad * 8);

  f32x4 o[4];
  float mi[4], li[4];
  #pragma unroll
  for (int r = 0; r < 4; ++r) { mi[r] = -1e30f; li[r] = 0.f; }
  #pragma unroll
  for (int d = 0; d < 4; ++d) o[d] = (f32x4){0.f, 0.f, 0.f, 0.f};

  const int skey = tid >> 3, sd = (tid & 7) * 8;

  for (int kt = 0; kt < 25; ++kt) {
    const int key = kt * 32 + skey;
    const int krow = key > NTOK - 1 ? NTOK - 1 : key;
    __syncthreads();
    *(uint4*)(Ks + skey * 72 + sd) = *(const uint4*)(kW + (bh * NTOK + krow) * 64 + sd);
    uint4 vv = *(const uint4*)(vW + (bh * NTOK + krow) * 64 + sd);
    unsigned short ve[8] = {
      (unsigned short)(vv.x & 0xffff), (unsigned short)(vv.x >> 16),
      (unsigned short)(vv.y & 0xffff), (unsigned short)(vv.y >> 16),
      (unsigned short)(vv.z & 0xffff), (unsigned short)(vv.z >> 16),
      (unsigned short)(vv.w & 0xffff), (unsigned short)(vv.w >> 16)};
    #pragma unroll
    for (int i = 0; i < 8; ++i) Vts[(sd + i) * 40 + skey] = (short)ve[i];
    __syncthreads();

    f32x4 s0 = (f32x4){0.f,0.f,0.f,0.f}, s1 = (f32x4){0.f,0.f,0.f,0.f};
    #pragma unroll
    for (int kk = 0; kk < 2; ++kk) {
      bf16x8 bk0 = *(const bf16x8*)(Ks + l15 * 72 + kk * 32 + quad * 8);
      bf16x8 bk1 = *(const bf16x8*)(Ks + (16 + l15) * 72 + kk * 32 + quad * 8);
      s0 = __builtin_amdgcn_mfma_f32_16x16x32_bf16(aq[kk], bk0, s0, 0, 0, 0);
      s1 = __builtin_amdgcn_mfma_f32_16x16x32_bf16(aq[kk], bk1, s1, 0, 0, 0);
    }
    const int key0 = kt * 32 + l15, key1 = kt * 32 + 16 + l15;
    short* pw = &Ps[wave][0];
    #pragma unroll
    for (int r = 0; r < 4; ++r) {
      float v0 = s0[r] * 0.125f; if (key0 > NTOK - 1) v0 = -1e30f;
      float v1 = s1[r] * 0.125f; if (key1 > NTOK - 1) v1 = -1e30f;
      float t = fmaxf(v0, v1);
      t = fmaxf(t, __shfl_xor(t, 1));
      t = fmaxf(t, __shfl_xor(t, 2));
      t = fmaxf(t, __shfl_xor(t, 4));
      t = fmaxf(t, __shfl_xor(t, 8));
      const float mn = fmaxf(mi[r], t);
      const float al = __expf(mi[r] - mn);
      const float p0 = __expf(v0 - mn);
      const float p1 = __expf(v1 - mn);
      float rs = p0 + p1;
      rs += __shfl_xor(rs, 1);
      rs += __shfl_xor(rs, 2);
      rs += __shfl_xor(rs, 4);
      rs += __shfl_xor(rs, 8);
      li[r] = li[r] * al + rs;
      mi[r] = mn;
      o[0][r] *= al; o[1][r] *= al; o[2][r] *= al; o[3][r] *= al;
      pw[(quad * 4 + r) * 40 + l15] = (short)f2bf(p0);
      pw[(quad * 4 + r) * 40 + 16 + l15] = (short)f2bf(p1);
    }
    bf16x8 ap = *(const bf16x8*)(pw + l15 * 40 + quad * 8);
    #pragma unroll
    for (int dg = 0; dg < 4; ++dg) {
      bf16x8 bv = *(const bf16x8*)(Vts + (dg * 16 + l15) * 40 + quad * 8);
      o[dg] = __builtin_amdgcn_mfma_f32_16x16x32_bf16(ap, bv, o[dg], 0, 0, 0);
    }
  }

  const int b = bh / NH, h = bh - b * NH;
  #pragma unroll
  for (int r = 0; r < 4; ++r) {
    const int q = qbase + quad * 4 + r;
    if (q < NTOK) {
      const float inv = 1.f / li[r];
      #pragma unroll
      for (int dg = 0; dg < 4; ++dg)
        ao[(b * NTOK + q) * CH + h * 64 + dg * 16 + l15] = f2bf(o[dg][r] * inv);
    }
  }
}

// ================= BLAS-faithful f32 cls chain + numpy-SIMD exp =================

__global__ __launch_bounds__(64) void q0_kernel(
    const float* __restrict__ x, const float* __restrict__ Wqkv, float* __restrict__ q0f)
{
  const int bh = blockIdx.x;
  const int b = bh / NH, h = bh - b * NH;
  const int d = threadIdx.x;
  const float* xr = x + (b * NTOK) * CH;
  const float* wr = Wqkv + (h * 64 + d) * CH;
  float p0 = 0.f, p1 = 0.f;
  for (int c = 0; c < 384; ++c) p0 = __fmaf_rn(xr[c], wr[c], p0);
  for (int c = 384; c < CH; ++c) p1 = __fmaf_rn(xr[c], wr[c], p1);
  q0f[bh * 64 + d] = __fadd_rn(p0, p1);
}

// kf[(bh*785+j)*64+d]: two KC=384 phases, each sequential-k FMA; combine with one add.
// v2: transposed LDS tiles [kk][row] + ds_read_b128 — numerics IDENTICAL to v1
// (same per-element FMA order), only the LDS access pattern changed.
__global__ __launch_bounds__(256) void kf_gemm(
    const float* __restrict__ x, const float* __restrict__ Wqkv, float* __restrict__ kf)
{
  __shared__ __align__(16) float Xt[32][68];   // [kk][j], pitch 68 (16B-aligned rows)
  __shared__ __align__(16) float Wt[32][68];   // [kk][d]
  const int bh = blockIdx.x;   // 0..191
  const int jt = blockIdx.y;   // 0..12
  const int b = bh / NH, h = bh - b * NH;
  const int tid = threadIdx.x;
  const int td = tid & 15, tj = tid >> 4;
  const int srow = tid >> 3;        // 0..31
  const int scol = (tid & 7) * 4;   // kk base 0..28

  int j0 = jt * 64 + srow;      if (j0 > NTOK - 1) j0 = NTOK - 1;
  int j1 = jt * 64 + srow + 32; if (j1 > NTOK - 1) j1 = NTOK - 1;
  const float* xp0 = x + (b * NTOK + j0) * CH + scol;
  const float* xp1 = x + (b * NTOK + j1) * CH + scol;
  const float* wp0 = Wqkv + (CH + h * 64 + srow) * CH + scol;
  const float* wp1 = Wqkv + (CH + h * 64 + srow + 32) * CH + scol;

  float accA[4][4];
  float out0[4][4];
  #pragma unroll
  for (int jj = 0; jj < 4; ++jj)
    #pragma unroll
    for (int dd = 0; dd < 4; ++dd) accA[jj][dd] = 0.f;

  for (int phase = 0; phase < 2; ++phase) {
    const int kbase = phase * 384;
    for (int kc = 0; kc < 384; kc += 32) {
      const int ko = kbase + kc;
      __syncthreads();
      {
        float4 xv = *(const float4*)(xp0 + ko);
        Xt[scol + 0][srow] = xv.x; Xt[scol + 1][srow] = xv.y;
        Xt[scol + 2][srow] = xv.z; Xt[scol + 3][srow] = xv.w;
        float4 xw = *(const float4*)(xp1 + ko);
        Xt[scol + 0][srow + 32] = xw.x; Xt[scol + 1][srow + 32] = xw.y;
        Xt[scol + 2][srow + 32] = xw.z; Xt[scol + 3][srow + 32] = xw.w;
        float4 wv = *(const float4*)(wp0 + ko);
        Wt[scol + 0][srow] = wv.x; Wt[scol + 1][srow] = wv.y;
        Wt[scol + 2][srow] = wv.z; Wt[scol + 3][srow] = wv.w;
        float4 ww = *(const float4*)(wp1 + ko);
        Wt[scol + 0][srow + 32] = ww.x; Wt[scol + 1][srow + 32] = ww.y;
        Wt[scol + 2][srow + 32] = ww.z; Wt[scol + 3][srow + 32] = ww.w;
      }
      __syncthreads();
      #pragma unroll 8
      for (int kk = 0; kk < 32; ++kk) {
        const float4 av = *(const float4*)&Xt[kk][tj * 4];
        const float4 bv = *(const float4*)&Wt[kk][td * 4];
        accA[0][0] = __fmaf_rn(av.x, bv.x, accA[0][0]);
        accA[0][1] = __fmaf_rn(av.x, bv.y, accA[0][1]);
        accA[0][2] = __fmaf_rn(av.x, bv.z, accA[0][2]);
        accA[0][3] = __fmaf_rn(av.x, bv.w, accA[0][3]);
        accA[1][0] = __fmaf_rn(av.y, bv.x, accA[1][0]);
        accA[1][1] = __fmaf_rn(av.y, bv.y, accA[1][1]);
        accA[1][2] = __fmaf_rn(av.y, bv.z, accA[1][2]);
        accA[1][3] = __fmaf_rn(av.y, bv.w, accA[1][3]);
        accA[2][0] = __fmaf_rn(av.z, bv.x, accA[2][0]);
        accA[2][1] = __fmaf_rn(av.z, bv.y, accA[2][1]);
        accA[2][2] = __fmaf_rn(av.z, bv.z, accA[2][2]);
        accA[2][3] = __fmaf_rn(av.z, bv.w, accA[2][3]);
        accA[3][0] = __fmaf_rn(av.w, bv.x, accA[3][0]);
        accA[3][1] = __fmaf_rn(av.w, bv.y, accA[3][1]);
        accA[3][2] = __fmaf_rn(av.w, bv.z, accA[3][2]);
        accA[3][3] = __fmaf_rn(av.w, bv.w, accA[3][3]);
      }
    }
    if (phase == 0) {
      #pragma unroll
      for (int jj = 0; jj < 4; ++jj)
        #pragma unroll
        for (int dd = 0; dd < 4; ++dd) { out0[jj][dd] = accA[jj][dd]; accA[jj][dd] = 0.f; }
    }
  }
  #pragma unroll
  for (int jj = 0; jj < 4; ++jj) {
    const int j = jt * 64 + tj * 4 + jj;
    if (j <= NTOK - 1) {
      #pragma unroll
      for (int dd = 0; dd < 4; ++dd)
        kf[(bh * NTOK + j) * 64 + td * 4 + dd] = __fadd_rn(out0[jj][dd], accA[jj][dd]);
    }
  }
}

DEVI float np_block8(const float* a, int off, int n) {
  float r[8];
  #pragma unroll
  for (int i = 0; i < 8; ++i) r[i] = a[off + i];
  int i = 8;
  const int lim = n - (n & 7);
  for (; i < lim; i += 8) {
    #pragma unroll
    for (int j = 0; j < 8; ++j) r[j] = __fadd_rn(r[j], a[off + i + j]);
  }
  float res = __fadd_rn(__fadd_rn(__fadd_rn(r[0], r[1]), __fadd_rn(r[2], r[3])),
                        __fadd_rn(__fadd_rn(r[4], r[5]), __fadd_rn(r[6], r[7])));
  for (; i < n; ++i) res = __fadd_rn(res, a[off + i]);
  return res;
}
DEVI float np_sum785(const float* a) {
  float p392 = __fadd_rn(__fadd_rn(np_block8(a, 0, 96),   np_block8(a, 96, 96)),
                         __fadd_rn(np_block8(a, 192, 96), np_block8(a, 288, 104)));
  float p393 = __fadd_rn(__fadd_rn(np_block8(a, 392, 96), np_block8(a, 488, 96)),
                         __fadd_rn(np_block8(a, 584, 96), np_block8(a, 680, 105)));
  return __fadd_rn(p392, p393);
}

// numpy SIMD f32 exp: Cody-Waite + rational P(5)/Q(2), FMA Horner, exact pow2 scale.
DEVI float np_expf(float x) {
  const float q = rintf(__fmul_rn(x, 1.442695040888963407f));
  float r = __fmaf_rn(q, -0.693145751953125f, x);
  r = __fmaf_rn(q, -1.428606765330187045e-06f, r);
  float num = __fmaf_rn(r, 5.082762527590693718096e-04f, 6.757896990527504603057e-03f);
  num = __fmaf_rn(num, r, 5.114512081637298353406e-02f);
  num = __fmaf_rn(num, r, 2.473615434895520810817e-01f);
  num = __fmaf_rn(num, r, 7.257664613233124478488e-01f);
  num = __fmaf_rn(num, r, 9.999999999980870924916e-01f);
  float den = __fmaf_rn(r, 2.159509375685829852307e-02f, -2.742335390411667452936e-01f);
  den = __fmaf_rn(den, r, 1.0f);
  return ldexpf(__fdiv_rn(num, den), (int)q);
}

__global__ __launch_bounds__(256) void cls_logits32(
    const float* __restrict__ kf, const float* __restrict__ q0f, float* __restrict__ part)
{
  __shared__ float q0s[64];
  __shared__ float lg[NTOK];
  __shared__ float ev[NTOK];
  __shared__ float red[256];
  const int bh = blockIdx.x;
  const int tid = threadIdx.x;
  if (tid < 64) q0s[tid] = q0f[bh * 64 + tid];
  __syncthreads();

  for (int j = tid; j < NTOK; j += 256) {
    const float* kr = kf + (bh * NTOK + j) * 64;
    float acc = 0.f;
    #pragma unroll
    for (int d = 0; d < 64; ++d) acc = __fmaf_rn(q0s[d], kr[d], acc);
    lg[j] = __fmul_rn(acc, 0.125f);
  }
  __syncthreads();

  float lm = -1e30f;
  for (int j = tid; j < NTOK; j += 256) lm = fmaxf(lm, lg[j]);
  red[tid] = lm; __syncthreads();
  for (int s = 128; s > 0; s >>= 1) {
    if (tid < s) red[tid] = fmaxf(red[tid], red[tid + s]);
    __syncthreads();
  }
  const float m = red[0];
  __syncthreads();

  for (int j = tid; j < NTOK; j += 256)
    ev[j] = np_expf(__fsub_rn(lg[j], m));
  __syncthreads();
  if (tid == 0) red[0] = np_sum785(ev);
  __syncthreads();
  const float Z = red[0];
  for (int j = tid; j < NTOK; j += 256)
    if (j >= 1) part[bh * 784 + (j - 1)] = __fdiv_rn(ev[j], Z);
}

__global__ __launch_bounds__(256) void cls_reduce32(
    const float* __restrict__ part, float* __restrict__ cls, float* __restrict__ cls_out)
{
  const int i = blockIdx.x * 256 + threadIdx.x;
  if (i >= 16 * 784) return;
  const int b = i / 784, t = i - b * 784;
  float s = part[(b * NH) * 784 + t];
  #pragma unroll
  for (int h = 1; h < NH; ++h) s = __fadd_rn(s, part[(b * NH + h) * 784 + t]);
  const float c = __fdiv_rn(s, 12.0f);
  cls[i] = c;
  cls_out[i] = c;
}

// Stable descending top-k (smaller index first on ties).
__global__ __launch_bounds__(256) void topk32(
    const float* __restrict__ cls, float* __restrict__ idx_out)
{
  __shared__ float vals[784];
  const int b = blockIdx.x, tid = threadIdx.x;
  for (int i = tid; i < 784; i += 256) vals[i] = cls[b * 784 + i];
  __syncthreads();
  for (int i = tid; i < 784; i += 256) {
    const float vi = vals[i];
    int rank = 0;
    for (int j = 0; j < 784; ++j) {
      const float vj = vals[j];
      rank += ((vj > vi) || (vj == vi && j < i)) ? 1 : 0;
    }
    if (rank < LEFT) idx_out[b * LEFT + rank] = (float)i;
  }
}

__global__ __launch_bounds__(256) void bcast_index(
    const float* __restrict__ idx, float* __restrict__ index_out)
{
  const int e = blockIdx.x * 256 + threadIdx.x;
  const int base = e * 8;
  if (base + 8 > 6746112) return;
  const int row = base / CH;
  const float v = idx[row];
  float4 q = {v, v, v, v};
  *(float4*)(index_out + base) = q;
  *(float4*)(index_out + base + 4) = q;
}

extern "C" void kernel_launch(void* const* d_in, const int* in_sizes, int n_in,
                              void* d_out, int out_size, void* d_ws, size_t ws_size,
                              hipStream_t stream) {
  const float* x     = (const float*)d_in[0];
  const float* Wqkv  = (const float*)d_in[1];
  const float* Wproj = (const float*)d_in[2];
  const float* bproj = (const float*)d_in[3];
  float* out = (float*)d_out;

  // d_out element offsets (f32): out | idx | index | cls_attn
  float* out_idx   = out + 9646080;
  float* out_index = out + 9654864;
  float* out_cls   = out + 16400976;

  char* ws = (char*)d_ws;
  unsigned short* qW  = (unsigned short*)(ws);               // 19,292,160 B
  unsigned short* kW  = (unsigned short*)(ws + 19292160);    // 19,292,160 B
  unsigned short* vW  = (unsigned short*)(ws + 38584320);    // 19,292,160 B
  unsigned short* aoW = (unsigned short*)(ws + 57876480);    // 19,292,160 B
  float* kf   = (float*)(ws);                                // 38,584,320 B (overlaps qW+kW, used after flash)
  float* q0f  = (float*)(ws + 38584320);                     // 49,152 B
  float* part = (float*)(ws + 38633472);                     // 602,112 B
  float* cls  = (float*)(ws + 39235584);                     // 50,176 B

  // 1) qkv projection -> q,k,v [B,H,N,64] bf16
  gemm128<0, float, float, unsigned short><<<dim3(99, 18), 256, 0, stream>>>(x, Wqkv, nullptr, qW, kW, vW);
  // 2) flash attention -> [B,N,C] bf16
  flash<<<dim3(13, 192), 256, 0, stream>>>(qW, kW, vW, aoW);
  // 3) output projection + bias -> f32 d_out[0 : 9646080]
  gemm128<1, unsigned short, float, float><<<dim3(99, 6), 256, 0, stream>>>(aoW, Wproj, bproj, out, nullptr, nullptr);
  // 4) BLAS-faithful f32 cls chain with numpy-SIMD exp (q/k/v regions now dead)
  q0_kernel<<<192, 64, 0, stream>>>(x, Wqkv, q0f);
  kf_gemm<<<dim3(192, 13), 256, 0, stream>>>(x, Wqkv, kf);
  cls_logits32<<<192, 256, 0, stream>>>(kf, q0f, part);
  cls_reduce32<<<49, 256, 0, stream>>>(part, cls, out_cls);
  // 5) top-k + index broadcast
  topk32<<<16, 256, 0, stream>>>(cls, out_idx);
  bcast_index<<<3294, 256, 0, stream>>>(out_idx, out_index);
}